// Round 4
// baseline (169.216 us; speedup 1.0000x reference)
//
#include <hip/hip_runtime.h>
#include <stdint.h>

typedef unsigned short u16;
typedef __bf16 bf16_t;
typedef bf16_t bf16x8 __attribute__((ext_vector_type(8)));
typedef float f32x4 __attribute__((ext_vector_type(4)));

static constexpr int P = 65536;  // H*W; D = C = 256

__device__ __forceinline__ float bfbits2f(uint32_t b) {
    union { uint32_t i; float f; } u; u.i = b << 16; return u.f;
}
__device__ __forceinline__ u16 f2bf(float f) {
    union { float f; uint32_t i; } u; u.f = f;
    uint32_t x = u.i + 0x7FFFu + ((u.i >> 16) & 1u);   // RNE
    return (u16)(x >> 16);
}
__device__ __forceinline__ uint32_t pack2(float a, float b) {
    return (uint32_t)f2bf(a) | ((uint32_t)f2bf(b) << 16);
}

// Runtime input-dtype sniff (insurance only; expected verdict: f32).
// u32 bits[14:7]: bf16-pair -> low element's exponent, in [96,135] for
// N(0,1) essentially always; f32 -> uniform mantissa bits (P~0.16).
__device__ __forceinline__ int detect_bf16_input(const void* Xg) {
    const uint32_t* Xu = (const uint32_t*)Xg;
    const int lane = (int)(threadIdx.x & 63);
    const uint32_t v = Xu[(size_t)lane * 131071u];   // in-bounds for either dtype
    const uint32_t e = (v >> 7) & 0xFFu;
    unsigned long long m = __ballot(e >= 96u && e <= 135u);
    return __popcll(m) >= 40;
}

// Kernel 1: rs[c] = scale[c] * 5 / max(||w_c||, 1e-8)  -> d_ws[0..255] (f32)
__global__ __launch_bounds__(256) void coshead_norms(
    const void* __restrict__ Xg, const void* __restrict__ Wg,
    const void* __restrict__ Sg, float* __restrict__ rs_ws)
{
    const int t = (int)threadIdx.x;
    const int bf = detect_bf16_input(Xg);
    float ssq = 0.f, sc;
    if (bf) {
        const u16* W16 = (const u16*)Wg;
        for (int i = 0; i < 32; ++i) {
            const uint4 vv = *(const uint4*)(W16 + (size_t)t * 256 + i * 8);
            const uint32_t ee[4] = {vv.x, vv.y, vv.z, vv.w};
#pragma unroll
            for (int d = 0; d < 4; ++d) {
                const float a = bfbits2f(ee[d] & 0xFFFFu), b = bfbits2f(ee[d] >> 16);
                ssq += a * a + b * b;
            }
        }
        sc = bfbits2f((uint32_t)((const u16*)Sg)[t]);
    } else {
        const float* W32 = (const float*)Wg;
        for (int i = 0; i < 64; ++i) {
            const f32x4 v = *(const f32x4*)(W32 + (size_t)t * 256 + i * 4);
            ssq += v[0]*v[0] + v[1]*v[1] + v[2]*v[2] + v[3]*v[3];
        }
        sc = ((const float*)Sg)[t];
    }
    rs_ws[t] = sc * 5.0f / fmaxf(sqrtf(ssq), 1e-8f);
}

// Kernel 2: out[c,p] = (W@X)[c,p] * rs[c] / max(||x_p||,1e-8), f32 out.
// 256 classes x 64 pixels per block, BK=64, 4 waves.
// MFMA 16x16x32_bf16 ONLY (fully verified layouts):
//   A frag: A[m=lane&15][k=quad*8+j], quad=lane>>4        [m120]
//   B frag: B^T stored [n][k], loaded identically to A    [m92/m97]
//   C/D   : col=lane&15, row=quad*4+reg                   [m89/m91]
// Plain LDS layouts (row-major, 128 B rows, NO swizzle) — correctness first.
__global__ __launch_bounds__(256, 3) void coshead_gemm(
    const void* __restrict__ Xg_, const void* __restrict__ Wg_,
    const float* __restrict__ rs_ws, float* __restrict__ Og)
{
    __shared__ char smem_[32768 + 8192];
    char* sA = smem_;            // [256 rows][64 k] bf16, 128 B/row
    char* sB = smem_ + 32768;    // [64 pix][64 k] bf16, 128 B/row

    const int t  = (int)threadIdx.x;
    const int l  = t & 63;
    const int w  = t >> 6;
    const int p0 = (int)blockIdx.x * 64;
    const int bf = detect_bf16_input(Xg_);

    const int g    = t & 7;      // pixel octet
    const int r    = t >> 3;     // k-pair row 0..31
    const int m16  = l & 15;
    const int quad = l >> 4;

    float ssq[8];
#pragma unroll
    for (int j = 0; j < 8; ++j) ssq[j] = 0.f;
    f32x4 acc[4][4];
#pragma unroll
    for (int a = 0; a < 4; ++a)
#pragma unroll
        for (int b = 0; b < 4; ++b)
#pragma unroll
            for (int i = 0; i < 4; ++i) acc[a][b][i] = 0.f;

    for (int kc = 0; kc < 4; ++kc) {
        if (bf) {
            // ---- A: thread t copies W row t, chunk kc (128 B) ----
            const uint4* src = (const uint4*)((const u16*)Wg_ + (size_t)t * 256 + kc * 64);
            uint4* dst = (uint4*)(sA + t * 128);
#pragma unroll
            for (int j = 0; j < 8; ++j) dst[j] = src[j];
            // ---- B: k-pair pack -> [pix][k]; fuse x ssq ----
            const u16* xp = (const u16*)Xg_ + (size_t)(2 * r + kc * 64) * P + p0 + g * 8;
            const uint4 v0 = *(const uint4*)xp;        // k=2r,   8 pixels
            const uint4 v1 = *(const uint4*)(xp + P);  // k=2r+1
            const uint32_t e0[4] = {v0.x, v0.y, v0.z, v0.w};
            const uint32_t e1[4] = {v1.x, v1.y, v1.z, v1.w};
#pragma unroll
            for (int d = 0; d < 4; ++d) {
                const float f00 = bfbits2f(e0[d] & 0xFFFFu), f01 = bfbits2f(e0[d] >> 16);
                const float f10 = bfbits2f(e1[d] & 0xFFFFu), f11 = bfbits2f(e1[d] >> 16);
                ssq[2 * d]     += f00 * f00 + f10 * f10;
                ssq[2 * d + 1] += f01 * f01 + f11 * f11;
                const uint32_t d0 = (e0[d] & 0xFFFFu) | (e1[d] << 16);
                const uint32_t d1 = (e0[d] >> 16) | (e1[d] & 0xFFFF0000u);
                *(uint32_t*)(sB + (g * 8 + 2 * d)     * 128 + r * 4) = d0;
                *(uint32_t*)(sB + (g * 8 + 2 * d + 1) * 128 + r * 4) = d1;
            }
        } else {
            // ---- A: f32 row t -> cvt bf16 -> LDS ----
            const float* wp = (const float*)Wg_ + (size_t)t * 256 + kc * 64;
#pragma unroll
            for (int j = 0; j < 8; ++j) {
                const f32x4 a = *(const f32x4*)(wp + j * 8);
                const f32x4 b = *(const f32x4*)(wp + j * 8 + 4);
                uint4 o;
                o.x = pack2(a[0], a[1]); o.y = pack2(a[2], a[3]);
                o.z = pack2(b[0], b[1]); o.w = pack2(b[2], b[3]);
                *(uint4*)(sA + t * 128 + j * 16) = o;
            }
            // ---- B: f32 -> cvt -> k-pair pack; fuse ssq on raw f32 ----
            const float* xp = (const float*)Xg_ + (size_t)(2 * r + kc * 64) * P + p0 + g * 8;
            const f32x4 c0  = *(const f32x4*)xp;
            const f32x4 c1  = *(const f32x4*)(xp + 4);
            const f32x4 d0v = *(const f32x4*)(xp + P);
            const f32x4 d1v = *(const f32x4*)(xp + P + 4);
            const float f0[8] = {c0[0], c0[1], c0[2], c0[3], c1[0], c1[1], c1[2], c1[3]};
            const float f1[8] = {d0v[0], d0v[1], d0v[2], d0v[3], d1v[0], d1v[1], d1v[2], d1v[3]};
#pragma unroll
            for (int j = 0; j < 8; ++j) {
                ssq[j] += f0[j] * f0[j] + f1[j] * f1[j];
                *(uint32_t*)(sB + (g * 8 + j) * 128 + r * 4) = pack2(f0[j], f1[j]);
            }
        }
        __syncthreads();
        // ---- MFMA: 2 k-steps of K=32; wave tile 64 classes x 64 pixels ----
#pragma unroll
        for (int kk = 0; kk < 2; ++kk) {
            bf16x8 af[4], bfr[4];
#pragma unroll
            for (int tm = 0; tm < 4; ++tm)
                af[tm] = *(const bf16x8*)(sA + (w * 64 + tm * 16 + m16) * 128 + kk * 64 + quad * 16);
#pragma unroll
            for (int tn = 0; tn < 4; ++tn)
                bfr[tn] = *(const bf16x8*)(sB + (tn * 16 + m16) * 128 + kk * 64 + quad * 16);
#pragma unroll
            for (int tm = 0; tm < 4; ++tm)
#pragma unroll
                for (int tn = 0; tn < 4; ++tn)
                    acc[tm][tn] = __builtin_amdgcn_mfma_f32_16x16x32_bf16(
                        af[tm], bfr[tn], acc[tm][tn], 0, 0, 0);
        }
        __syncthreads();
    }

    // ---- epilogue: x-norms via LDS transpose-reduce ----
    float* xs   = (float*)sA;    // [32][64] partial ssq
    float* xinv = (float*)sB;    // [64]
#pragma unroll
    for (int j = 0; j < 8; ++j) xs[r * 64 + g * 8 + j] = ssq[j];
    __syncthreads();
    if (t < 64) {
        float sx = 0.f;
#pragma unroll
        for (int rr = 0; rr < 32; ++rr) sx += xs[rr * 64 + t];
        xinv[t] = 1.0f / fmaxf(sqrtf(sx), 1e-8f);
    }
    __syncthreads();

    // ---- scaled f32 store.  class = w*64 + tm*16 + quad*4 + i ; pixel = p0 + tn*16 + m16 ----
#pragma unroll
    for (int tn = 0; tn < 4; ++tn) {
        const float inv = xinv[tn * 16 + m16];
#pragma unroll
        for (int tm = 0; tm < 4; ++tm) {
            const int cbase = w * 64 + tm * 16 + quad * 4;
            const f32x4 rs4 = *(const f32x4*)(rs_ws + cbase);
#pragma unroll
            for (int i = 0; i < 4; ++i) {
                Og[(size_t)(cbase + i) * P + p0 + tn * 16 + m16] =
                    acc[tm][tn][i] * rs4[i] * inv;
            }
        }
    }
}

extern "C" void kernel_launch(void* const* d_in, const int* in_sizes, int n_in,
                              void* d_out, int out_size, void* d_ws, size_t ws_size,
                              hipStream_t stream) {
    (void)out_size; (void)ws_size;
    // Bind inputs by element count (robust to ordering): X=16.7M, W=65536, S=256.
    const void* X = d_in[0];
    const void* W = d_in[1];
    const void* S = d_in[2];
    for (int i = 0; i < n_in; ++i) {
        if (in_sizes[i] == 256 * 65536) X = d_in[i];
        else if (in_sizes[i] == 256 * 256) W = d_in[i];
        else if (in_sizes[i] == 256)      S = d_in[i];
    }
    float* rs = (float*)d_ws;
    coshead_norms<<<dim3(1), dim3(256), 0, stream>>>(X, W, S, rs);
    coshead_gemm<<<dim3(1024), dim3(256), 0, stream>>>(X, W, rs, (float*)d_out);
}

// Round 5
// 135.266 us; speedup vs baseline: 1.2510x; 1.2510x over previous
//
#include <hip/hip_runtime.h>
#include <stdint.h>

typedef unsigned short u16;
typedef __bf16 bf16_t;
typedef bf16_t bf16x8 __attribute__((ext_vector_type(8)));
typedef float f32x4 __attribute__((ext_vector_type(4)));

static constexpr int P = 65536;  // H*W; D = C = 256

__device__ __forceinline__ float bfbits2f(uint32_t b) {
    union { uint32_t i; float f; } u; u.i = b << 16; return u.f;
}
__device__ __forceinline__ u16 f2bf(float f) {
    union { float f; uint32_t i; } u; u.f = f;
    uint32_t x = u.i + 0x7FFFu + ((u.i >> 16) & 1u);   // RNE
    return (u16)(x >> 16);
}
__device__ __forceinline__ uint32_t pack2(float a, float b) {
    return (uint32_t)f2bf(a) | ((uint32_t)f2bf(b) << 16);
}

// Runtime input-dtype sniff (insurance; verdict on this harness: f32).
__device__ __forceinline__ int detect_bf16_input(const void* Xg) {
    const uint32_t* Xu = (const uint32_t*)Xg;
    const int lane = (int)(threadIdx.x & 63);
    const uint32_t v = Xu[(size_t)lane * 131071u];
    const uint32_t e = (v >> 7) & 0xFFu;
    unsigned long long m = __ballot(e >= 96u && e <= 135u);
    return __popcll(m) >= 40;
}

// Kernel 1: rs[c] = scale[c] * 5 / max(||w_c||, 1e-8).
// 256 blocks x 64 lanes: one class per block, fully coalesced 1 KB row read,
// wave shuffle reduction. (R4's 1-block version was ~80 us, latency-bound.)
__global__ __launch_bounds__(64) void coshead_norms(
    const void* __restrict__ Xg, const void* __restrict__ Wg,
    const void* __restrict__ Sg, float* __restrict__ rs_ws)
{
    const int c    = (int)blockIdx.x;
    const int lane = (int)threadIdx.x;
    const int bf   = detect_bf16_input(Xg);
    float s;
    if (bf) {
        const uint2 v = *(const uint2*)((const u16*)Wg + (size_t)c * 256 + lane * 4);
        const float a = bfbits2f(v.x & 0xFFFFu), b = bfbits2f(v.x >> 16);
        const float d = bfbits2f(v.y & 0xFFFFu), e = bfbits2f(v.y >> 16);
        s = a * a + b * b + d * d + e * e;
    } else {
        const f32x4 v = *(const f32x4*)((const float*)Wg + (size_t)c * 256 + lane * 4);
        s = v[0] * v[0] + v[1] * v[1] + v[2] * v[2] + v[3] * v[3];
    }
    s += __shfl_xor(s, 1);  s += __shfl_xor(s, 2);  s += __shfl_xor(s, 4);
    s += __shfl_xor(s, 8);  s += __shfl_xor(s, 16); s += __shfl_xor(s, 32);
    if (lane == 0) {
        const float sc = bf ? bfbits2f((uint32_t)((const u16*)Sg)[c])
                            : ((const float*)Sg)[c];
        rs_ws[c] = sc * 5.0f / fmaxf(sqrtf(s), 1e-8f);
    }
}

// Kernel 2: out[c,p] = (W@X)[c,p] * rs[c] / max(||x_p||,1e-8), f32 out.
// 256 classes x 64 pixels per block, BK=64, 4 waves; MFMA 16x16x32_bf16.
// Verified fragment layouts (m120/m92/m89). XOR-granule swizzled LDS:
//   sA: granule gk (k/8) of row at column gk^(row&7)         -> all free
//   sB: granule of pix at column gk^(pix&7)^(pix>>3)         -> 2-way (free)
__global__ __launch_bounds__(256, 3) void coshead_gemm(
    const void* __restrict__ Xg_, const void* __restrict__ Wg_,
    const float* __restrict__ rs_ws, float* __restrict__ Og)
{
    __shared__ char smem_[32768 + 8192];
    char* sA = smem_;            // [256 rows][8 granules x 16 B], swizzled
    char* sB = smem_ + 32768;    // [64 pix][8 granules x 16 B], swizzled

    const int t  = (int)threadIdx.x;
    const int l  = t & 63;
    const int w  = t >> 6;
    const int p0 = (int)blockIdx.x * 64;
    const int bf = detect_bf16_input(Xg_);

    const int g    = t & 7;      // pixel octet / A k-granule
    const int r    = t >> 3;     // k-pair row 0..31 / A row base 0..31
    const int m16  = l & 15;
    const int quad = l >> 4;

    float ssq[8];
#pragma unroll
    for (int j = 0; j < 8; ++j) ssq[j] = 0.f;
    f32x4 acc[4][4];
#pragma unroll
    for (int a = 0; a < 4; ++a)
#pragma unroll
        for (int b = 0; b < 4; ++b)
#pragma unroll
            for (int i = 0; i < 4; ++i) acc[a][b][i] = 0.f;

    for (int kc = 0; kc < 4; ++kc) {
        if (bf) {
            // ---- A: thread t -> granule g of rows r+32i (coalesced 128 B/8 lanes) ----
#pragma unroll
            for (int i = 0; i < 8; ++i) {
                const int row = i * 32 + r;
                const uint4 v = *(const uint4*)((const u16*)Wg_ + (size_t)row * 256 + kc * 64 + g * 8);
                *(uint4*)(sA + row * 128 + ((g ^ (row & 7)) * 16)) = v;
            }
            // ---- B: k-pair pack -> [pix][k] swizzled; fuse x ssq ----
            const u16* xp = (const u16*)Xg_ + (size_t)(2 * r + kc * 64) * P + p0 + g * 8;
            const uint4 v0 = *(const uint4*)xp;
            const uint4 v1 = *(const uint4*)(xp + P);
            const uint32_t e0[4] = {v0.x, v0.y, v0.z, v0.w};
            const uint32_t e1[4] = {v1.x, v1.y, v1.z, v1.w};
#pragma unroll
            for (int d = 0; d < 4; ++d) {
                const float f00 = bfbits2f(e0[d] & 0xFFFFu), f01 = bfbits2f(e0[d] >> 16);
                const float f10 = bfbits2f(e1[d] & 0xFFFFu), f11 = bfbits2f(e1[d] >> 16);
                ssq[2 * d]     += f00 * f00 + f10 * f10;
                ssq[2 * d + 1] += f01 * f01 + f11 * f11;
                const uint32_t d0 = (e0[d] & 0xFFFFu) | (e1[d] << 16);
                const uint32_t d1 = (e0[d] >> 16) | (e1[d] & 0xFFFF0000u);
                const int pj0 = g * 8 + 2 * d, pj1 = pj0 + 1;
                *(uint32_t*)(sB + pj0 * 128 + (((r >> 2) ^ (pj0 & 7) ^ g) * 16) + (r & 3) * 4) = d0;
                *(uint32_t*)(sB + pj1 * 128 + (((r >> 2) ^ (pj1 & 7) ^ g) * 16) + (r & 3) * 4) = d1;
            }
        } else {
            // ---- A: f32, thread t -> granule g of rows r+32i (256 B/8 lanes) ----
#pragma unroll
            for (int i = 0; i < 8; ++i) {
                const int row = i * 32 + r;
                const float* wp = (const float*)Wg_ + (size_t)row * 256 + kc * 64 + g * 8;
                const f32x4 a = *(const f32x4*)wp;
                const f32x4 b = *(const f32x4*)(wp + 4);
                uint4 o;
                o.x = pack2(a[0], a[1]); o.y = pack2(a[2], a[3]);
                o.z = pack2(b[0], b[1]); o.w = pack2(b[2], b[3]);
                *(uint4*)(sA + row * 128 + ((g ^ (row & 7)) * 16)) = o;
            }
            // ---- B: f32 -> cvt -> k-pair pack swizzled; fuse ssq on raw f32 ----
            const float* xp = (const float*)Xg_ + (size_t)(2 * r + kc * 64) * P + p0 + g * 8;
            const f32x4 c0  = *(const f32x4*)xp;
            const f32x4 c1  = *(const f32x4*)(xp + 4);
            const f32x4 d0v = *(const f32x4*)(xp + P);
            const f32x4 d1v = *(const f32x4*)(xp + P + 4);
            const float f0[8] = {c0[0], c0[1], c0[2], c0[3], c1[0], c1[1], c1[2], c1[3]};
            const float f1[8] = {d0v[0], d0v[1], d0v[2], d0v[3], d1v[0], d1v[1], d1v[2], d1v[3]};
#pragma unroll
            for (int j = 0; j < 8; ++j) {
                ssq[j] += f0[j] * f0[j] + f1[j] * f1[j];
                const int pix = g * 8 + j;
                *(uint32_t*)(sB + pix * 128 + (((r >> 2) ^ (pix & 7) ^ g) * 16) + (r & 3) * 4) =
                    pack2(f0[j], f1[j]);
            }
        }
        __syncthreads();
        // ---- MFMA: 2 K=32 steps; wave tile 64 classes x 64 pixels ----
#pragma unroll
        for (int kk = 0; kk < 2; ++kk) {
            bf16x8 af[4], bfr[4];
#pragma unroll
            for (int tm = 0; tm < 4; ++tm) {
                const int row = w * 64 + tm * 16 + m16;
                af[tm] = *(const bf16x8*)(sA + row * 128 + (((kk * 4 + quad) ^ (row & 7)) * 16));
            }
#pragma unroll
            for (int tn = 0; tn < 4; ++tn) {
                const int pix = tn * 16 + m16;
                bfr[tn] = *(const bf16x8*)(sB + pix * 128 +
                           (((kk * 4 + quad) ^ (pix & 7) ^ (pix >> 3)) * 16));
            }
#pragma unroll
            for (int tm = 0; tm < 4; ++tm)
#pragma unroll
                for (int tn = 0; tn < 4; ++tn)
                    acc[tm][tn] = __builtin_amdgcn_mfma_f32_16x16x32_bf16(
                        af[tm], bfr[tn], acc[tm][tn], 0, 0, 0);
        }
        __syncthreads();
    }

    // ---- epilogue: x-norms via LDS transpose-reduce ----
    float* xs   = (float*)sA;    // [32][64] partial ssq
    float* xinv = (float*)sB;    // [64]
#pragma unroll
    for (int j = 0; j < 8; ++j) xs[r * 64 + g * 8 + j] = ssq[j];
    __syncthreads();
    if (t < 64) {
        float sx = 0.f;
#pragma unroll
        for (int rr = 0; rr < 32; ++rr) sx += xs[rr * 64 + t];
        xinv[t] = 1.0f / fmaxf(sqrtf(sx), 1e-8f);
    }
    __syncthreads();

    // ---- scaled f32 store. class = w*64+tm*16+quad*4+i ; pixel = p0+tn*16+m16 ----
#pragma unroll
    for (int tn = 0; tn < 4; ++tn) {
        const float inv = xinv[tn * 16 + m16];
#pragma unroll
        for (int tm = 0; tm < 4; ++tm) {
            const int cbase = w * 64 + tm * 16 + quad * 4;
            const f32x4 rs4 = *(const f32x4*)(rs_ws + cbase);
#pragma unroll
            for (int i = 0; i < 4; ++i) {
                Og[(size_t)(cbase + i) * P + p0 + tn * 16 + m16] =
                    acc[tm][tn][i] * rs4[i] * inv;
            }
        }
    }
}

extern "C" void kernel_launch(void* const* d_in, const int* in_sizes, int n_in,
                              void* d_out, int out_size, void* d_ws, size_t ws_size,
                              hipStream_t stream) {
    (void)out_size; (void)ws_size;
    const void* X = d_in[0];
    const void* W = d_in[1];
    const void* S = d_in[2];
    for (int i = 0; i < n_in; ++i) {
        if (in_sizes[i] == 256 * 65536) X = d_in[i];
        else if (in_sizes[i] == 256 * 256) W = d_in[i];
        else if (in_sizes[i] == 256)      S = d_in[i];
    }
    float* rs = (float*)d_ws;
    coshead_norms<<<dim3(256), dim3(64), 0, stream>>>(X, W, S, rs);
    coshead_gemm<<<dim3(1024), dim3(256), 0, stream>>>(X, W, rs, (float*)d_out);
}